// Round 1
// baseline (3216.925 us; speedup 1.0000x reference)
//
#include <hip/hip_runtime.h>

// Problem constants (from reference): B=512, T=1024, I=64, H=64, 3H=192.
#define NB 512
#define NT 1024
#define NI 64
#define NH 64
#define G3 192

// One block per batch element. 384 threads = 6 waves.
// Thread t owns one row of (Wih | Whh) per layer, held in registers:
//   t <  192 : row t of Wih (input-side gates, vector = x_t  [layer0] / h0 [layer1])
//   t >= 192 : row t-192 of Whh (recurrent gates, vector = h0 [layer0] / h1 [layer1])
// Wave 0 (threads 0..63) computes the element-wise gates + head.
__global__ __launch_bounds__(384) void gru2_fused(
    const float* __restrict__ x,
    const float* __restrict__ Wih0, const float* __restrict__ Whh0,
    const float* __restrict__ bih0, const float* __restrict__ bhh0,
    const float* __restrict__ Wih1, const float* __restrict__ Whh1,
    const float* __restrict__ bih1, const float* __restrict__ bhh1,
    const float* __restrict__ fcw,  const float* __restrict__ fcb,
    float* __restrict__ out)
{
    const int tid = threadIdx.x;
    const int b   = blockIdx.x;

    __shared__ __align__(16) float xbuf[2][NI]; // double-buffered x_t
    __shared__ __align__(16) float h0s[NH];
    __shared__ __align__(16) float h1s[NH];
    __shared__ __align__(16) float gA[384];     // layer-0: gx(0..191) | gh(192..383)
    __shared__ __align__(16) float gB[384];     // layer-1: same layout

    const bool isIh = (tid < G3);
    const int  row  = isIh ? tid : (tid - G3);

    // ---- load weight rows into registers (one-time; weights are L2-resident) ----
    float4 w0[16], w1[16];
    {
        const float4* s0 = (const float4*)((isIh ? Wih0 : Whh0) + row * 64);
        const float4* s1 = (const float4*)((isIh ? Wih1 : Whh1) + row * 64);
        #pragma unroll
        for (int j = 0; j < 16; ++j) { w0[j] = s0[j]; w1[j] = s1[j]; }
    }
    const float bias0 = isIh ? bih0[row] : bhh0[row];
    const float bias1 = isIh ? bih1[row] : bhh1[row];
    const float fw    = (tid < NH) ? fcw[tid] : 0.0f;
    const float fb    = fcb[0];

    const float* xb = x + (size_t)b * NT * NI;

    if (tid < NI) xbuf[0][tid] = xb[tid];
    if (tid < NH) { h0s[tid] = 0.0f; h1s[tid] = 0.0f; }
    __syncthreads();

    float xnext = 0.0f;
    for (int t = 0; t < NT; ++t) {
        // prefetch x_{t+1} (consumed in gates-0, stored to the other buffer)
        if (tid < NI && (t + 1) < NT)
            xnext = xb[(size_t)(t + 1) * NI + tid];

        // ---- phase A: layer-0 matvecs (all 384 threads, 64 FMAs each) ----
        {
            const float4* v = (const float4*)(isIh ? xbuf[t & 1] : h0s);
            float acc = bias0;
            #pragma unroll
            for (int j = 0; j < 16; ++j) {
                float4 vv = v[j];
                float4 ww = w0[j];
                acc = fmaf(ww.x, vv.x, acc);
                acc = fmaf(ww.y, vv.y, acc);
                acc = fmaf(ww.z, vv.z, acc);
                acc = fmaf(ww.w, vv.w, acc);
            }
            gA[tid] = acc;
        }
        __syncthreads();

        // ---- gates layer 0 (wave 0 only) ----
        if (tid < NH) {
            float xr = gA[tid], xz = gA[NH + tid], xn = gA[2 * NH + tid];
            float hr = gA[G3 + tid], hz = gA[G3 + NH + tid], hn = gA[G3 + 2 * NH + tid];
            float r = 1.0f / (1.0f + __expf(-(xr + hr)));
            float z = 1.0f / (1.0f + __expf(-(xz + hz)));
            float a = xn + r * hn;                    // bhh_n rides inside hn (matches ref)
            float n = 1.0f - 2.0f / (__expf(2.0f * a) + 1.0f); // tanh(a), saturation-safe
            h0s[tid] = (1.0f - z) * n + z * h0s[tid];
            if ((t + 1) < NT) xbuf[(t + 1) & 1][tid] = xnext;
        }
        __syncthreads();

        // ---- phase B: layer-1 matvecs ----
        {
            const float4* v = (const float4*)(isIh ? h0s : h1s);
            float acc = bias1;
            #pragma unroll
            for (int j = 0; j < 16; ++j) {
                float4 vv = v[j];
                float4 ww = w1[j];
                acc = fmaf(ww.x, vv.x, acc);
                acc = fmaf(ww.y, vv.y, acc);
                acc = fmaf(ww.z, vv.z, acc);
                acc = fmaf(ww.w, vv.w, acc);
            }
            gB[tid] = acc;
        }
        __syncthreads();

        // ---- gates layer 1 + linear head (wave 0 only) ----
        if (tid < NH) {
            float xr = gB[tid], xz = gB[NH + tid], xn = gB[2 * NH + tid];
            float hr = gB[G3 + tid], hz = gB[G3 + NH + tid], hn = gB[G3 + 2 * NH + tid];
            float r = 1.0f / (1.0f + __expf(-(xr + hr)));
            float z = 1.0f / (1.0f + __expf(-(xz + hz)));
            float a = xn + r * hn;
            float n = 1.0f - 2.0f / (__expf(2.0f * a) + 1.0f);
            float hnew = (1.0f - z) * n + z * h1s[tid];
            h1s[tid] = hnew;

            float p = hnew * fw;
            #pragma unroll
            for (int off = 32; off > 0; off >>= 1)
                p += __shfl_down(p, off, 64);
            if (tid == 0) out[(size_t)b * NT + t] = p + fb;
        }
        __syncthreads();
    }
}

extern "C" void kernel_launch(void* const* d_in, const int* in_sizes, int n_in,
                              void* d_out, int out_size, void* d_ws, size_t ws_size,
                              hipStream_t stream) {
    (void)in_sizes; (void)n_in; (void)d_ws; (void)ws_size; (void)out_size;
    gru2_fused<<<NB, 384, 0, stream>>>(
        (const float*)d_in[0],                      // x
        (const float*)d_in[1], (const float*)d_in[2],   // W_ih0, W_hh0
        (const float*)d_in[3], (const float*)d_in[4],   // b_ih0, b_hh0
        (const float*)d_in[5], (const float*)d_in[6],   // W_ih1, W_hh1
        (const float*)d_in[7], (const float*)d_in[8],   // b_ih1, b_hh1
        (const float*)d_in[9], (const float*)d_in[10],  // fc_w, fc_b
        (float*)d_out);
}

// Round 2
// 1879.516 us; speedup vs baseline: 1.7116x; 1.7116x over previous
//
#include <hip/hip_runtime.h>

// B=512, T=1024, I=H=64, 3H=192.
#define NB 512
#define NT 1024
#define NH 64
#define G3 192
#define CH 8            // timesteps staged per superstep
#define NCH (NT / CH)   // 128 supersteps

// One block per batch element, one GRU layer per pass.
// 384 threads: tid<192 -> input-side row (Wih), tid>=192 -> recurrent row (Whh).
// Each thread holds exactly ONE 64-float weight row in registers (16 float4 =
// 64 VGPR) -- small enough that the compiler keeps it resident (round-1 held
// two rows = 256 VGPR, got rematerialized into per-step L2 reloads).
__global__ __launch_bounds__(384, 2) void gru_layer(
    const float* in,                      // [B][T][64]  (may alias hseq in pass 2)
    const float* __restrict__ Wih, const float* __restrict__ Whh,   // [192][64]
    const float* __restrict__ bih, const float* __restrict__ bhh,   // [192]
    float* hseq)                          // [B][T][64] out
{
    const int tid = threadIdx.x;
    const int b   = blockIdx.x;
    const bool isIh = (tid < G3);
    const int  row  = isIh ? tid : (tid - G3);

    __shared__ __align__(16) float xin[2][CH * NH]; // double-buffered input chunks (4 KB)
    __shared__ __align__(16) float hbuf[NH];
    __shared__ __align__(16) float g[384];          // gx rows 0..191 | gh rows 192..383

    // ---- weight row -> registers (one-time) ----
    float4 w[16];
    {
        const float4* src = (const float4*)((isIh ? Wih : Whh) + row * 64);
        #pragma unroll
        for (int j = 0; j < 16; ++j) w[j] = src[j];
    }
    const float bias = isIh ? bih[row] : bhh[row];

    const float* inb  = in   + (size_t)b * NT * NH;
    float*       hout = hseq + (size_t)b * NT * NH;

    // stage chunk 0 (128 float4 = 8 rows of 64 floats, coalesced)
    if (tid < 128) ((float4*)&xin[0][0])[tid] = ((const float4*)inb)[tid];
    if (tid < NH) hbuf[tid] = 0.0f;
    __syncthreads();

    for (int tc = 0; tc < NCH; ++tc) {
        // issue prefetch of next chunk early; consumed at superstep end.
        float4 pf;
        if (tid < 128) {
            int tcn = (tc + 1) & (NCH - 1);     // wraps to 0 on last iter (dead data)
            pf = ((const float4*)(inb + (size_t)tcn * CH * NH))[tid];
        }

        for (int s = 0; s < CH; ++s) {
            // ---- matvec: one 64-dot per thread, 4-way ILP ----
            const float4* v = (const float4*)(isIh ? &xin[tc & 1][s * NH] : hbuf);
            float a0 = 0.f, a1 = 0.f, a2 = 0.f, a3 = 0.f;
            #pragma unroll
            for (int j = 0; j < 16; ++j) {
                float4 vv = v[j];
                float4 ww = w[j];
                a0 = fmaf(ww.x, vv.x, a0);
                a1 = fmaf(ww.y, vv.y, a1);
                a2 = fmaf(ww.z, vv.z, a2);
                a3 = fmaf(ww.w, vv.w, a3);
            }
            g[tid] = ((a0 + a1) + (a2 + a3)) + bias;
            __syncthreads();

            // ---- gates (wave 0) ----
            if (tid < NH) {
                float xr = g[tid],      xz = g[NH + tid],      xn = g[2*NH + tid];
                float hr = g[G3 + tid], hz = g[G3 + NH + tid], hn = g[G3 + 2*NH + tid];
                float r = 1.0f / (1.0f + __expf(-(xr + hr)));
                float z = 1.0f / (1.0f + __expf(-(xz + hz)));
                float a = xn + r * hn;                       // bhh_n rides inside hn
                float n = 1.0f - 2.0f / (__expf(2.0f * a) + 1.0f); // tanh, sat-safe
                float hnew = (1.0f - z) * n + z * hbuf[tid];
                hbuf[tid] = hnew;
                hout[(size_t)(tc * CH + s) * NH + tid] = hnew;
            }
            __syncthreads();
        }

        // commit prefetched chunk to the other LDS buffer
        if (tid < 128) ((float4*)&xin[(tc + 1) & 1][0])[tid] = pf;
        __syncthreads();
    }
}

// out[bt] = dot(hseq[bt][:], fcw) + fcb  -- memory-bound, trivially parallel.
__global__ __launch_bounds__(256) void head_k(
    const float* __restrict__ hseq, const float* __restrict__ fcw,
    const float* __restrict__ fcb, float* __restrict__ out)
{
    int i = blockIdx.x * 256 + threadIdx.x;         // bt in [0, B*T)
    const float4* hp = (const float4*)(hseq + (size_t)i * NH);
    const float4* wp = (const float4*)fcw;
    float a0 = 0.f, a1 = 0.f, a2 = 0.f, a3 = 0.f;
    #pragma unroll
    for (int j = 0; j < 16; ++j) {
        float4 h = hp[j], w = wp[j];
        a0 = fmaf(h.x, w.x, a0);
        a1 = fmaf(h.y, w.y, a1);
        a2 = fmaf(h.z, w.z, a2);
        a3 = fmaf(h.w, w.w, a3);
    }
    out[i] = ((a0 + a1) + (a2 + a3)) + fcb[0];
}

extern "C" void kernel_launch(void* const* d_in, const int* in_sizes, int n_in,
                              void* d_out, int out_size, void* d_ws, size_t ws_size,
                              hipStream_t stream) {
    (void)in_sizes; (void)n_in; (void)out_size; (void)ws_size;
    const float* x    = (const float*)d_in[0];
    const float* Wih0 = (const float*)d_in[1];
    const float* Whh0 = (const float*)d_in[2];
    const float* bih0 = (const float*)d_in[3];
    const float* bhh0 = (const float*)d_in[4];
    const float* Wih1 = (const float*)d_in[5];
    const float* Whh1 = (const float*)d_in[6];
    const float* bih1 = (const float*)d_in[7];
    const float* bhh1 = (const float*)d_in[8];
    const float* fcw  = (const float*)d_in[9];
    const float* fcb  = (const float*)d_in[10];

    float* hseq = (float*)d_ws;   // needs B*T*H*4 = 134.2 MB of workspace

    // layer 0: x -> hseq
    gru_layer<<<NB, 384, 0, stream>>>(x, Wih0, Whh0, bih0, bhh0, hseq);
    // layer 1: hseq -> hseq (row read precedes row overwrite within each block)
    gru_layer<<<NB, 384, 0, stream>>>(hseq, Wih1, Whh1, bih1, bhh1, hseq);
    // head
    head_k<<<2048, 256, 0, stream>>>(hseq, fcw, fcb, (float*)d_out);
}

// Round 5
// 1774.762 us; speedup vs baseline: 1.8126x; 1.0590x over previous
//
#include <hip/hip_runtime.h>

// B=512, T=1024, I=H=64, 3H=192.
#define NB 512
#define NT 1024
#define NH 64
#define G3 192
#define CH 8            // timesteps staged per superstep
#define NCH (NT / CH)   // 128 supersteps

// One block per batch element, one GRU layer per pass.
// 384 threads: tid<192 -> input-side row (Wih), tid>=192 -> recurrent row (Whh).
// Each thread holds ONE 64-float weight row in registers. Round 2 showed
// (VGPR_Count=60 < 64) that the compiler rematerialized the weight loads into
// the t-loop; the asm "+v" pin below makes the loaded values opaque so they
// MUST stay register-resident.
__global__ __launch_bounds__(384, 2) void gru_layer(
    const float* in,                      // [B][T][64]  (aliases hseq in pass 2)
    const float* __restrict__ Wih, const float* __restrict__ Whh,   // [192][64]
    const float* __restrict__ bih, const float* __restrict__ bhh,   // [192]
    float* hseq)                          // [B][T][64] out
{
    const int tid = threadIdx.x;
    const int b   = blockIdx.x;
    const bool isIh = (tid < G3);
    const int  row  = isIh ? tid : (tid - G3);

    __shared__ __align__(16) float xin[2][CH * NH]; // double-buffered input chunks
    __shared__ __align__(16) float hbuf[NH];        // current hidden state
    __shared__ __align__(16) float hist[CH * NH];   // h outputs of this superstep
    __shared__ __align__(16) float g[384];          // gx rows 0..191 | gh rows 192..383

    // ---- weight row -> registers (one-time), pinned via opaque asm ----
    float4 w[16];
    {
        const float4* src = (const float4*)((isIh ? Wih : Whh) + row * 64);
        #pragma unroll
        for (int j = 0; j < 16; ++j) w[j] = src[j];
    }
    #pragma unroll
    for (int j = 0; j < 16; ++j)
        asm volatile("" : "+v"(w[j].x), "+v"(w[j].y), "+v"(w[j].z), "+v"(w[j].w));

    const float bias = isIh ? bih[row] : bhh[row];

    const float* inb  = in   + (size_t)b * NT * NH;
    float*       hout = hseq + (size_t)b * NT * NH;

    // stage chunk 0 (128 float4, coalesced)
    if (tid < 128) ((float4*)&xin[0][0])[tid] = ((const float4*)inb)[tid];
    if (tid < NH) hbuf[tid] = 0.0f;
    __syncthreads();

    for (int tc = 0; tc < NCH; ++tc) {
        // issue prefetch of next chunk early; committed at superstep end.
        float4 pf;
        if (tid < 128) {
            int tcn = (tc + 1) & (NCH - 1);     // wraps on last iter (dead data)
            pf = ((const float4*)(inb + (size_t)tcn * CH * NH))[tid];
        }

        for (int s = 0; s < CH; ++s) {
            // ---- matvec: one 64-dot per thread, 4-way ILP.
            // All lanes of a wave read the same LDS address -> broadcast.
            const float4* v = (const float4*)(isIh ? &xin[tc & 1][s * NH] : hbuf);
            float a0 = 0.f, a1 = 0.f, a2 = 0.f, a3 = 0.f;
            #pragma unroll
            for (int j = 0; j < 16; ++j) {
                float4 vv = v[j];
                float4 ww = w[j];
                a0 = fmaf(ww.x, vv.x, a0);
                a1 = fmaf(ww.y, vv.y, a1);
                a2 = fmaf(ww.z, vv.z, a2);
                a3 = fmaf(ww.w, vv.w, a3);
            }
            g[tid] = ((a0 + a1) + (a2 + a3)) + bias;
            __syncthreads();

            // ---- gates (wave 0 only) ----
            if (tid < NH) {
                float xr = g[tid],      xz = g[NH + tid],      xn = g[2*NH + tid];
                float hr = g[G3 + tid], hz = g[G3 + NH + tid], hn = g[G3 + 2*NH + tid];
                float r = __builtin_amdgcn_rcpf(1.0f + __expf(-(xr + hr)));
                float z = __builtin_amdgcn_rcpf(1.0f + __expf(-(xz + hz)));
                float a = xn + r * hn;                    // bhh_n rides inside hn
                float n = 1.0f - 2.0f * __builtin_amdgcn_rcpf(__expf(2.0f * a) + 1.0f);
                float hnew = (1.0f - z) * n + z * hbuf[tid];
                hbuf[tid] = hnew;
                hist[s * NH + tid] = hnew;     // global store deferred to superstep end
            }
            __syncthreads();
        }

        // flush this superstep's h rows (coalesced), commit prefetched chunk
        if (tid < 128) {
            ((float4*)(hout + (size_t)tc * CH * NH))[tid] = ((const float4*)hist)[tid];
            ((float4*)&xin[(tc + 1) & 1][0])[tid] = pf;
        }
        __syncthreads();
    }
}

// out[bt] = dot(hseq[bt][:], fcw) + fcb  -- memory-bound, trivially parallel.
__global__ __launch_bounds__(256) void head_k(
    const float* __restrict__ hseq, const float* __restrict__ fcw,
    const float* __restrict__ fcb, float* __restrict__ out)
{
    int i = blockIdx.x * 256 + threadIdx.x;         // bt in [0, B*T)
    const float4* hp = (const float4*)(hseq + (size_t)i * NH);
    const float4* wp = (const float4*)fcw;
    float a0 = 0.f, a1 = 0.f, a2 = 0.f, a3 = 0.f;
    #pragma unroll
    for (int j = 0; j < 16; ++j) {
        float4 h = hp[j], w = wp[j];
        a0 = fmaf(h.x, w.x, a0);
        a1 = fmaf(h.y, w.y, a1);
        a2 = fmaf(h.z, w.z, a2);
        a3 = fmaf(h.w, w.w, a3);
    }
    out[i] = ((a0 + a1) + (a2 + a3)) + fcb[0];
}

extern "C" void kernel_launch(void* const* d_in, const int* in_sizes, int n_in,
                              void* d_out, int out_size, void* d_ws, size_t ws_size,
                              hipStream_t stream) {
    (void)in_sizes; (void)n_in; (void)out_size; (void)ws_size;
    const float* x    = (const float*)d_in[0];
    const float* Wih0 = (const float*)d_in[1];
    const float* Whh0 = (const float*)d_in[2];
    const float* bih0 = (const float*)d_in[3];
    const float* bhh0 = (const float*)d_in[4];
    const float* Wih1 = (const float*)d_in[5];
    const float* Whh1 = (const float*)d_in[6];
    const float* bih1 = (const float*)d_in[7];
    const float* bhh1 = (const float*)d_in[8];
    const float* fcw  = (const float*)d_in[9];
    const float* fcb  = (const float*)d_in[10];

    float* hseq = (float*)d_ws;   // B*T*H*4 = 134.2 MB of workspace

    gru_layer<<<NB, 384, 0, stream>>>(x,    Wih0, Whh0, bih0, bhh0, hseq);
    gru_layer<<<NB, 384, 0, stream>>>(hseq, Wih1, Whh1, bih1, bhh1, hseq);
    head_k<<<2048, 256, 0, stream>>>(hseq, fcw, fcb, (float*)d_out);
}